// Round 1
// baseline (5026.436 us; speedup 1.0000x reference)
//
#include <hip/hip_runtime.h>

#define SEQ 2048
#define D 128

// ---------------------------------------------------------------------------
// Kernel 1: per-step J-independent quantities (fully parallel).
// Block b handles step s=b (l = s+1):
//   alpha_i = k_s . q_i      (i <= s)
//   beta_i  = v_s . v_i
//   kqq[s]  = (1/l) sum alpha_i^2          = k^T Sqq_l k
//   sl[s]   = (1/l) sum alpha_i beta_i     = k^T Sqv_l v
//   vv[s]   = v_s . v_s
//   U[s][c] = (1/l) sum_i q_i[c] alpha_i   = (Sqq_l k)[c]
// ---------------------------------------------------------------------------
__global__ __launch_bounds__(256) void precompute_kernel(
    const float* __restrict__ q, const float* __restrict__ k, const float* __restrict__ v,
    float* __restrict__ U, float* __restrict__ sl, float* __restrict__ kqq,
    float* __restrict__ vv)
{
    const int s = blockIdx.x;
    const int l = s + 1;
    const int tid = threadIdx.x;

    __shared__ float ks[D];
    __shared__ float vs[D];
    __shared__ float alpha[SEQ];
    __shared__ float red[8];
    __shared__ float upart[256];

    if (tid < D) ks[tid] = k[s * D + tid];
    else if (tid < 2 * D) vs[tid - D] = v[s * D + (tid - D)];
    __syncthreads();

    float p_a2 = 0.f, p_ab = 0.f;
    for (int i = tid; i <= s; i += 256) {
        const float4* qr = (const float4*)(q + (size_t)i * D);
        const float4* vr = (const float4*)(v + (size_t)i * D);
        float a = 0.f, b = 0.f;
#pragma unroll
        for (int j = 0; j < D / 4; ++j) {
            float4 q4 = qr[j];
            float4 v4 = vr[j];
            a += q4.x * ks[4 * j + 0] + q4.y * ks[4 * j + 1] + q4.z * ks[4 * j + 2] + q4.w * ks[4 * j + 3];
            b += v4.x * vs[4 * j + 0] + v4.y * vs[4 * j + 1] + v4.z * vs[4 * j + 2] + v4.w * vs[4 * j + 3];
        }
        alpha[i] = a;
        p_a2 += a * a;
        p_ab += a * b;
        if (i == s) vv[s] = b;  // v_s . v_s
    }
#pragma unroll
    for (int off = 1; off < 64; off <<= 1) {
        p_a2 += __shfl_xor(p_a2, off);
        p_ab += __shfl_xor(p_ab, off);
    }
    const int wid = tid >> 6;
    if ((tid & 63) == 0) { red[wid] = p_a2; red[4 + wid] = p_ab; }
    __syncthreads();  // also makes alpha[] visible to everyone
    if (tid == 0) {
        kqq[s] = (red[0] + red[1] + red[2] + red[3]) / (float)l;
        sl[s]  = (red[4] + red[5] + red[6] + red[7]) / (float)l;
    }

    // pass 2: U[s][c] = (1/l) sum_i q[i][c] * alpha[i], split i over 2 halves
    const int c = tid & (D - 1);
    const int h = tid >> 7;  // 0 or 1
    float acc = 0.f;
    for (int i = h; i <= s; i += 2) acc += q[(size_t)i * D + c] * alpha[i];
    upart[tid] = acc;
    __syncthreads();
    if (tid < D) U[(size_t)s * D + tid] = (upart[tid] + upart[tid + D]) / (float)l;
}

// ---------------------------------------------------------------------------
// Kernel 2: sequential scan, single persistent workgroup (1024 threads).
// J kept twice in registers: jrow[j] = J[r][16g+j], jcol[j] = J[16g+j][r]
// (r = tid>>3 in 0..127, g = tid&7), so both J@q and J^T@v are 16 FMAs +
// a 3-level shuffle reduce. Scalar invariants (SJ, AJJ, trSvv) in fp64 on
// thread 0.
// ---------------------------------------------------------------------------
__global__ __launch_bounds__(1024) void scan_kernel(
    const float* __restrict__ q, const float* __restrict__ k, const float* __restrict__ v,
    const float* __restrict__ U, const float* __restrict__ sl_arr,
    const float* __restrict__ kqq_arr, const float* __restrict__ vv_arr,
    float* __restrict__ out)  // [0,2048) costs | [2048,4096) updated | [4096,...) J
{
    const int tid  = threadIdx.x;
    const int r    = tid >> 3;   // 0..127
    const int g    = tid & 7;    // 0..7
    const int c0   = g * 16;
    const int wv   = tid >> 6;   // wave 0..15
    const int lane = tid & 63;

    float jrow[16], jcol[16];
#pragma unroll
    for (int j = 0; j < 16; ++j) { jrow[j] = 0.f; jcol[j] = 0.f; }

    __shared__ float vecs[2][4][D];   // [buf][q,k,v,u][128]
    __shared__ float wred[16][4];     // per-wave partials: Jq.v, |Jq|^2, (J^T v).u
    __shared__ float dec[4];          // wf_c, wi_c, mode

    double SJ = 0.0, AJJ = 0.0, trSvv = 0.0;

    for (int s = 0; s < SEQ; ++s) {
        const int buf = s & 1;
        if (tid < 512) {
            const int which = tid >> 7;   // 0:q 1:k 2:v 3:u
            const int idx = tid & 127;
            const float* src = (which == 0) ? q : (which == 1) ? k : (which == 2) ? v : U;
            vecs[buf][which][idx] = src[(size_t)s * D + idx];
        }
        __syncthreads();  // B1
        const float* qs = vecs[buf][0];
        const float* ks = vecs[buf][1];
        const float* vs = vecs[buf][2];
        const float* us = vecs[buf][3];

        // partial dot products
        float pq = 0.f, pv = 0.f;
#pragma unroll
        for (int j = 0; j < 16; ++j) {
            pq += jrow[j] * qs[c0 + j];   // row r of J . q
            pv += jcol[j] * vs[c0 + j];   // col r of J . v
        }
#pragma unroll
        for (int off = 1; off < 8; off <<= 1) {
            pq += __shfl_xor(pq, off);
            pv += __shfl_xor(pv, off);
        }
        // pq = (Jq)[r], pv = (J^T v)[r] on all 8 lanes of the r-group
        float x = (g == 0) ? pq * vs[r] : (g == 1) ? pq * pq : (g == 2) ? pv * us[r] : 0.f;
#pragma unroll
        for (int off = 8; off < 64; off <<= 1) x += __shfl_xor(x, off);
        if (lane < 3) wred[wv][lane] = x;
        __syncthreads();  // B2

        if (wv == 0) {
            float a0 = 0.f, a1 = 0.f, a2 = 0.f;
            if (lane < 16) { a0 = wred[lane][0]; a1 = wred[lane][1]; a2 = wred[lane][2]; }
#pragma unroll
            for (int off = 1; off < 16; off <<= 1) {
                a0 += __shfl_xor(a0, off);
                a1 += __shfl_xor(a1, off);
                a2 += __shfl_xor(a2, off);
            }
            if (lane == 0) {
                const double Jqv = (double)a0;   // v^T J q
                const double Jq2 = (double)a1;   // ||J q||^2
                const double A_Jl = (double)a2;  // v^T J Sqq_new k
                const double l = (double)(s + 1);
                const double a = (l - 1.0) / l, b = 1.0 / l;
                const double s_l  = (double)sl_arr[s];
                const double kqq  = (double)kqq_arr[s];
                const double vvd  = (double)vv_arr[s];

                trSvv = a * trSvv + b * vvd;
                SJ    = a * SJ    + b * Jqv;    // tr(J Sqv_new)
                AJJ   = a * AJJ   + b * Jq2;    // tr(J Sqq_new J^T)

                const double A_ll = vvd * kqq;
                const bool first = (s == 0);
                const double A_JJ_s = (first || AJJ == 0.0) ? 1.0 : AJJ;
                const double A_ll_s = (first || A_ll == 0.0) ? 1.0 : A_ll;
                const double denom = AJJ * A_ll - A_Jl * A_Jl;
                const double denom_s = (first || denom == 0.0) ? 1.0 : denom;
                const double margin = s_l - A_Jl * (SJ / A_JJ_s);
                const double wf = (A_ll * SJ - A_Jl * s_l) / denom_s;
                const double wi = (AJJ * s_l - A_Jl * SJ) / denom_s;
                double wf_c, wi_c;
                if (wi <= 0.0)      { wf_c = SJ / A_JJ_s; wi_c = 0.0; }
                else if (wf <= 0.0) { wf_c = 0.0;         wi_c = s_l / A_ll_s; }
                else                { wf_c = wf;          wi_c = wi; }
                const bool do_update = margin > 0.0;

                float mode;
                if (first) {
                    mode = 2.f;
                    SJ  = s_l;     // tr(vk^T Sqv) = k^T Sqv v
                    AJJ = A_ll;    // tr(vk^T Sqq kv^T) = (v.v)(k^T Sqq k)
                } else if (do_update) {
                    mode = 1.f;
                    SJ  = wf_c * SJ + wi_c * s_l;
                    AJJ = wf_c * wf_c * AJJ + 2.0 * wf_c * wi_c * A_Jl + wi_c * wi_c * A_ll;
                } else {
                    mode = 0.f;
                }
                dec[0] = (float)wf_c;
                dec[1] = (float)wi_c;
                dec[2] = mode;
                out[s] = (float)(0.5 * trSvv - SJ + 0.5 * AJJ);
                out[SEQ + s] = (first || do_update) ? 1.f : 0.f;
            }
        }
        __syncthreads();  // B3

        const float mode = dec[2];
        if (mode == 2.f) {           // first: J = outer(v, k)
            const float vr = vs[r], kr = ks[r];
#pragma unroll
            for (int j = 0; j < 16; ++j) {
                jrow[j] = vr * ks[c0 + j];
                jcol[j] = vs[c0 + j] * kr;
            }
        } else if (mode == 1.f) {    // J = wf*J + wi*outer(v,k)
            const float wf_c = dec[0], wi_c = dec[1];
            const float vr = vs[r], kr = ks[r];
#pragma unroll
            for (int j = 0; j < 16; ++j) {
                jrow[j] = wf_c * jrow[j] + wi_c * (vr * ks[c0 + j]);
                jcol[j] = wf_c * jcol[j] + wi_c * (vs[c0 + j] * kr);
            }
        }
        // next iteration loads into the other buffer; dec/wred re-writes are
        // separated from this step's reads by B1/B2 of the next iteration.
    }

    // final J (row-major [d_v][d_k])
#pragma unroll
    for (int j = 0; j < 16; ++j) out[2 * SEQ + r * D + c0 + j] = jrow[j];
}

extern "C" void kernel_launch(void* const* d_in, const int* in_sizes, int n_in,
                              void* d_out, int out_size, void* d_ws, size_t ws_size,
                              hipStream_t stream) {
    (void)in_sizes; (void)n_in; (void)out_size; (void)ws_size;
    const float* q = (const float*)d_in[0];
    const float* k = (const float*)d_in[1];
    const float* v = (const float*)d_in[2];
    float* out = (float*)d_out;

    float* U   = (float*)d_ws;            // SEQ*D floats (1 MB)
    float* sl  = U + (size_t)SEQ * D;     // SEQ
    float* kqq = sl + SEQ;                // SEQ
    float* vv  = kqq + SEQ;               // SEQ

    precompute_kernel<<<SEQ, 256, 0, stream>>>(q, k, v, U, sl, kqq, vv);
    scan_kernel<<<1, 1024, 0, stream>>>(q, k, v, U, sl, kqq, vv, out);
}

// Round 2
// 4903.350 us; speedup vs baseline: 1.0251x; 1.0251x over previous
//
#include <hip/hip_runtime.h>

#define SEQ 2048
#define D 128

// ---------------------------------------------------------------------------
// Kernel 1: per-step J-independent quantities (fully parallel), UNNORMALIZED:
//   alpha_i = k_s . q_i      (i <= s)
//   kqq[s]  = sum alpha_i^2          = l * (k^T Sqq_l k)
//   sl[s]   = sum alpha_i (v_s.v_i)  = l * (k^T Sqv_l v)
//   vv[s]   = v_s . v_s
//   U[s][c] = sum_i q_i[c] alpha_i   = l * (Sqq_l k)[c]
//   invl[s] = 1.0 / l   (fp64, for cost rescale)
// ---------------------------------------------------------------------------
__global__ __launch_bounds__(256) void precompute_kernel(
    const float* __restrict__ q, const float* __restrict__ k, const float* __restrict__ v,
    float* __restrict__ U, float* __restrict__ sl, float* __restrict__ kqq,
    float* __restrict__ vv, double* __restrict__ invl)
{
    const int s = blockIdx.x;
    const int tid = threadIdx.x;

    __shared__ float ks[D];
    __shared__ float vs[D];
    __shared__ float alpha[SEQ];
    __shared__ float red[8];
    __shared__ float upart[256];

    if (tid < D) ks[tid] = k[s * D + tid];
    else if (tid < 2 * D) vs[tid - D] = v[s * D + (tid - D)];
    __syncthreads();

    float p_a2 = 0.f, p_ab = 0.f;
    for (int i = tid; i <= s; i += 256) {
        const float4* qr = (const float4*)(q + (size_t)i * D);
        const float4* vr = (const float4*)(v + (size_t)i * D);
        float a = 0.f, b = 0.f;
#pragma unroll
        for (int j = 0; j < D / 4; ++j) {
            float4 q4 = qr[j];
            float4 v4 = vr[j];
            a += q4.x * ks[4 * j + 0] + q4.y * ks[4 * j + 1] + q4.z * ks[4 * j + 2] + q4.w * ks[4 * j + 3];
            b += v4.x * vs[4 * j + 0] + v4.y * vs[4 * j + 1] + v4.z * vs[4 * j + 2] + v4.w * vs[4 * j + 3];
        }
        alpha[i] = a;
        p_a2 += a * a;
        p_ab += a * b;
        if (i == s) vv[s] = b;  // v_s . v_s
    }
#pragma unroll
    for (int off = 1; off < 64; off <<= 1) {
        p_a2 += __shfl_xor(p_a2, off);
        p_ab += __shfl_xor(p_ab, off);
    }
    const int wid = tid >> 6;
    if ((tid & 63) == 0) { red[wid] = p_a2; red[4 + wid] = p_ab; }
    __syncthreads();  // also makes alpha[] visible to everyone
    if (tid == 0) {
        kqq[s] = red[0] + red[1] + red[2] + red[3];
        sl[s]  = red[4] + red[5] + red[6] + red[7];
        invl[s] = 1.0 / (double)(s + 1);
    }

    // pass 2: U[s][c] = sum_i q[i][c] * alpha[i], split i over 2 halves
    const int c = tid & (D - 1);
    const int h = tid >> 7;  // 0 or 1
    float acc = 0.f;
    for (int i = h; i <= s; i += 2) acc += q[(size_t)i * D + c] * alpha[i];
    upart[tid] = acc;
    __syncthreads();
    if (tid < D) U[(size_t)s * D + tid] = upart[tid] + upart[tid + D];
}

// ---------------------------------------------------------------------------
// Kernel 2: sequential scan, one 256-thread workgroup (4 waves).
// wave w: rb = w>>1 (row block), g = w&1 (column half) — both wave-uniform
// (readfirstlane) so q/u/k row slices load as SCALAR (s_load) operands.
// Thread (w, lane): rows r = rb*64+lane, holds J[r][g*64 .. g*64+63] in VGPRs.
// Per step: partial Jq, Ju dots -> LDS pair-combine (B1) -> 3-scalar wave
// reduce -> LDS (B2) -> redundant fp64 decision chain on ALL threads (no
// broadcast barrier) -> rank-1 J update. Unnormalized sums: SJ' += v.Jq,
// AJJ' += |Jq|^2, trSvv' += v.v; decisions are scale-invariant; margin test
// is division-free (AJJ_s > 0 always).
// ---------------------------------------------------------------------------
__global__ __launch_bounds__(256) void scan_kernel(
    const float* __restrict__ q, const float* __restrict__ k, const float* __restrict__ v,
    const float* __restrict__ U, const float* __restrict__ sl_arr,
    const float* __restrict__ kqq_arr, const float* __restrict__ vv_arr,
    const double* __restrict__ invl_arr,
    float* __restrict__ out)  // [0,2048) costs | [2048,4096) updated | [4096,...) J
{
    const int tid  = threadIdx.x;
    const int lane = tid & 63;
    const int w  = __builtin_amdgcn_readfirstlane(tid >> 6);  // 0..3, uniform
    const int g  = w & 1;          // column half
    const int rb = w >> 1;         // row block
    const int r  = rb * 64 + lane; // my row
    const int c0 = g * 64;         // my column base

    float jr[64];
#pragma unroll
    for (int j = 0; j < 64; ++j) jr[j] = 0.f;

    __shared__ float2 part[4][64];  // per-wave (pq, pu) partials
    __shared__ float  wred[4][2];   // per-wave reduced scalars

    double SJ = 0.0, AJJ = 0.0, trSvv = 0.0;

    for (int s = 0; s < SEQ; ++s) {
        const float* qrow = q + (size_t)s * D + c0;  // uniform -> s_load
        const float* urow = U + (size_t)s * D + c0;  // uniform -> s_load
        const float* krow = k + (size_t)s * D + c0;  // uniform -> s_load
        const float vr  = v[(size_t)s * D + r];      // per-lane
        const float slf = sl_arr[s];
        const float kqf = kqq_arr[s];
        const float vvf = vv_arr[s];
        const double invl = invl_arr[s];

        // partial dots over my 64 columns (4 accumulators to break dep chains)
        float pq0 = 0.f, pq1 = 0.f, pu0 = 0.f, pu1 = 0.f;
#pragma unroll
        for (int j = 0; j < 64; j += 2) {
            pq0 = fmaf(jr[j],     qrow[j],     pq0);
            pq1 = fmaf(jr[j + 1], qrow[j + 1], pq1);
            pu0 = fmaf(jr[j],     urow[j],     pu0);
            pu1 = fmaf(jr[j + 1], urow[j + 1], pu1);
        }
        float pq = pq0 + pq1, pu = pu0 + pu1;

        part[w][lane] = make_float2(pq, pu);
        __syncthreads();  // B1
        {
            float2 o = part[w ^ 1][lane];  // partner wave: same rows, other cols
            pq += o.x;
            pu += o.y;
        }

        // per-wave scalar contributions (rows split over rb; g picks quantity)
        float x0, x1 = 0.f;
        if (g == 0) {
            x0 = vr * pq;          // -> v^T J q
            x1 = pq * pq;          // -> |J q|^2
#pragma unroll
            for (int off = 1; off < 64; off <<= 1) {
                x0 += __shfl_xor(x0, off);
                x1 += __shfl_xor(x1, off);
            }
        } else {
            x0 = vr * pu;          // -> v^T J u  (A_Jl)
#pragma unroll
            for (int off = 1; off < 64; off <<= 1) x0 += __shfl_xor(x0, off);
        }
        if (lane == 0) { wred[w][0] = x0; wred[w][1] = x1; }
        __syncthreads();  // B2

        const double Jqv = (double)wred[0][0] + (double)wred[2][0];
        const double Jq2 = (double)wred[0][1] + (double)wred[2][1];
        const double AJl = (double)wred[1][0] + (double)wred[3][0];

        // ---- redundant fp64 decision chain (identical on all threads) ----
        trSvv += (double)vvf;
        SJ    += Jqv;
        AJJ   += Jq2;
        const double s_l  = (double)slf;
        const double A_ll = (double)vvf * (double)kqf;
        const bool first = (s == 0);
        const double AJJ_s  = (first || AJJ == 0.0)  ? 1.0 : AJJ;   // > 0 always
        const double A_ll_s = (first || A_ll == 0.0) ? 1.0 : A_ll;
        const double denom   = AJJ * A_ll - AJl * AJl;
        const double denom_s = (first || denom == 0.0) ? 1.0 : denom;
        const double rden = 1.0 / denom_s;
        const double wf = (A_ll * SJ - AJl * s_l) * rden;
        const double wi = (AJJ * s_l - AJl * SJ) * rden;
        double wf_c, wi_c;
        if (wi <= 0.0)      { wf_c = SJ / AJJ_s;  wi_c = 0.0; }
        else if (wf <= 0.0) { wf_c = 0.0;         wi_c = s_l / A_ll_s; }
        else                { wf_c = wf;          wi_c = wi; }
        const bool do_update = (s_l * AJJ_s - AJl * SJ) > 0.0;  // margin * AJJ_s

        int mode;
        if (first) {
            mode = 2;
            SJ  = s_l;    // tr(vk^T Sqv') = k^T Sqv' v
            AJJ = A_ll;   // (v.v)(k^T Sqq' k)
        } else if (do_update) {
            mode = 1;
            const double nSJ = wf_c * SJ + wi_c * s_l;
            AJJ = wf_c * wf_c * AJJ + 2.0 * wf_c * wi_c * AJl + wi_c * wi_c * A_ll;
            SJ = nSJ;
        } else {
            mode = 0;
        }

        if (tid == 0) {
            out[s] = (float)((0.5 * trSvv - SJ + 0.5 * AJJ) * invl);
            out[SEQ + s] = (mode != 0) ? 1.f : 0.f;
        }

        // ---- J update (wave-uniform branch) ----
        if (mode == 2) {
#pragma unroll
            for (int j = 0; j < 64; ++j) jr[j] = vr * krow[j];
        } else if (mode == 1) {
            const float wff = (float)wf_c;
            const float wvr = (float)wi_c * vr;
#pragma unroll
            for (int j = 0; j < 64; ++j) jr[j] = fmaf(jr[j], wff, wvr * krow[j]);
        }
    }

    // final J (row-major [d_v][d_k])
#pragma unroll
    for (int j = 0; j < 64; ++j) out[2 * SEQ + (size_t)r * D + c0 + j] = jr[j];
}

extern "C" void kernel_launch(void* const* d_in, const int* in_sizes, int n_in,
                              void* d_out, int out_size, void* d_ws, size_t ws_size,
                              hipStream_t stream) {
    (void)in_sizes; (void)n_in; (void)out_size; (void)ws_size;
    const float* q = (const float*)d_in[0];
    const float* k = (const float*)d_in[1];
    const float* v = (const float*)d_in[2];
    float* out = (float*)d_out;

    float* U    = (float*)d_ws;             // SEQ*D floats (1 MB)
    float* sl   = U + (size_t)SEQ * D;      // SEQ
    float* kqq  = sl + SEQ;                 // SEQ
    float* vv   = kqq + SEQ;                // SEQ
    double* invl = (double*)(vv + SEQ);     // SEQ doubles (8B-aligned: offset 1073152)

    precompute_kernel<<<SEQ, 256, 0, stream>>>(q, k, v, U, sl, kqq, vv, invl);
    scan_kernel<<<1, 256, 0, stream>>>(q, k, v, U, sl, kqq, vv, invl, out);
}

// Round 3
// 4061.839 us; speedup vs baseline: 1.2375x; 1.2072x over previous
//
#include <hip/hip_runtime.h>

#define SEQ 2048
#define D 128

// ---------------------------------------------------------------------------
// Kernel 1: per-step J-independent quantities (fully parallel), UNNORMALIZED:
//   alpha_i = k_s . q_i      (i <= s)
//   kqq[s]  = sum alpha_i^2          = l * (k^T Sqq_l k)
//   sl[s]   = sum alpha_i (v_s.v_i)  = l * (k^T Sqv_l v)
//   vv[s]   = v_s . v_s
//   U[s][c] = sum_i q_i[c] alpha_i   = l * (Sqq_l k)[c]
//   invl[s] = 1.0 / l   (fp64, for cost rescale)
// ---------------------------------------------------------------------------
__global__ __launch_bounds__(256) void precompute_kernel(
    const float* __restrict__ q, const float* __restrict__ k, const float* __restrict__ v,
    float* __restrict__ U, float* __restrict__ sl, float* __restrict__ kqq,
    float* __restrict__ vv, double* __restrict__ invl)
{
    const int s = blockIdx.x;
    const int tid = threadIdx.x;

    __shared__ float ks[D];
    __shared__ float vs[D];
    __shared__ float alpha[SEQ];
    __shared__ float red[8];
    __shared__ float upart[256];

    if (tid < D) ks[tid] = k[s * D + tid];
    else if (tid < 2 * D) vs[tid - D] = v[s * D + (tid - D)];
    __syncthreads();

    float p_a2 = 0.f, p_ab = 0.f;
    for (int i = tid; i <= s; i += 256) {
        const float4* qr = (const float4*)(q + (size_t)i * D);
        const float4* vr = (const float4*)(v + (size_t)i * D);
        float a = 0.f, b = 0.f;
#pragma unroll
        for (int j = 0; j < D / 4; ++j) {
            float4 q4 = qr[j];
            float4 v4 = vr[j];
            a += q4.x * ks[4 * j + 0] + q4.y * ks[4 * j + 1] + q4.z * ks[4 * j + 2] + q4.w * ks[4 * j + 3];
            b += v4.x * vs[4 * j + 0] + v4.y * vs[4 * j + 1] + v4.z * vs[4 * j + 2] + v4.w * vs[4 * j + 3];
        }
        alpha[i] = a;
        p_a2 += a * a;
        p_ab += a * b;
        if (i == s) vv[s] = b;  // v_s . v_s
    }
#pragma unroll
    for (int off = 1; off < 64; off <<= 1) {
        p_a2 += __shfl_xor(p_a2, off);
        p_ab += __shfl_xor(p_ab, off);
    }
    const int wid = tid >> 6;
    if ((tid & 63) == 0) { red[wid] = p_a2; red[4 + wid] = p_ab; }
    __syncthreads();  // also makes alpha[] visible to everyone
    if (tid == 0) {
        kqq[s] = red[0] + red[1] + red[2] + red[3];
        sl[s]  = red[4] + red[5] + red[6] + red[7];
        invl[s] = 1.0 / (double)(s + 1);
    }

    // pass 2: U[s][c] = sum_i q[i][c] * alpha[i], split i over 2 halves
    const int c = tid & (D - 1);
    const int h = tid >> 7;  // 0 or 1
    float acc = 0.f;
    for (int i = h; i <= s; i += 2) acc += q[(size_t)i * D + c] * alpha[i];
    upart[tid] = acc;
    __syncthreads();
    if (tid < D) U[(size_t)s * D + tid] = upart[tid] + upart[tid + D];
}

// ---------------------------------------------------------------------------
// Kernel 2: sequential scan, one 256-thread workgroup (4 waves, 1 per SIMD).
// __launch_bounds__(256, 1): allow full VGPR budget so jr[64] stays in regs
// (round-2 regression: default occupancy target spilled jr to scratch ->
// VGPR_Count=52, FETCH_SIZE=3.1GB).
// wave w: rb=w>>1 (row block), g=w&1 (column half); thread owns
// J[rb*64+lane][g*64 .. g*64+63] in VGPRs.
// Operand pipeline: q/u rows staged through a 3-phase LDS ring; per-lane
// coalesced global loads issued 3 steps ahead, ds_write 2 steps ahead,
// reads (wave-uniform broadcast ds_read_b128) in the current step. k row is
// read from global in the post-B2 zone (fp64 chain hides latency). v element
// and per-step scalars are register-prefetched.
// Barriers: 2 per step (B1 covers partial exchange + staging visibility,
// B2 covers the 3-scalar cross-wave reduce).
// ---------------------------------------------------------------------------
__global__ __launch_bounds__(256, 1) void scan_kernel(
    const float* __restrict__ q, const float* __restrict__ k, const float* __restrict__ v,
    const float* __restrict__ U, const float* __restrict__ sl_arr,
    const float* __restrict__ kqq_arr, const float* __restrict__ vv_arr,
    const double* __restrict__ invl_arr,
    float* __restrict__ out)  // [0,2048) costs | [2048,4096) updated | [4096,...) J
{
    const int tid  = threadIdx.x;
    const int lane = tid & 63;
    const int w  = __builtin_amdgcn_readfirstlane(tid >> 6);  // 0..3, uniform
    const int g  = w & 1;          // column half
    const int rb = w >> 1;         // row block
    const int r  = rb * 64 + lane; // my row
    const int c0 = g * 64;         // my column base

    float jr[64];
#pragma unroll
    for (int j = 0; j < 64; ++j) jr[j] = 0.f;

    __shared__ float  sbuf[3][2][D];   // [phase][q,u][128] staging ring
    __shared__ float2 part[4][64];     // per-wave (pq, pu) partials
    __shared__ float  wred[4][2];      // per-wave reduced scalars

    // staging roles: threads 0-127 stage q-row element, 128-255 stage u-row
    const bool roleA = tid < 128;
    const int  sidx  = roleA ? tid : tid - 128;

    // ---- prologue: stage steps 0,1 into phases 0,1; regs hold step 2 ----
    for (int t = 0; t < 2; ++t) {
        if (roleA) sbuf[t][0][sidx] = q[(size_t)t * D + sidx];
        else       sbuf[t][1][sidx] = U[(size_t)t * D + sidx];
    }
    float gstage = roleA ? q[(size_t)2 * D + sidx] : U[(size_t)2 * D + sidx];
    float vcur = v[r], v1 = v[(size_t)1 * D + r], v2 = v[(size_t)2 * D + r];
    float  slc = sl_arr[0], kqc = kqq_arr[0], vvc = vv_arr[0];
    double invc = invl_arr[0];
    __syncthreads();

    double SJ = 0.0, AJJ = 0.0, trSvv = 0.0;

    for (int s = 0; s < SEQ; ++s) {
        const int p  = s % 3;
        const int pw = (s + 2) % 3;  // phase being written (data for step s+2)

        // ---- A: dots over my 64 columns (LDS broadcast reads) ----
        const float4* q4 = (const float4*)&sbuf[p][0][c0];
        const float4* u4 = (const float4*)&sbuf[p][1][c0];
        float pqa = 0.f, pqb = 0.f, pqc = 0.f, pqd = 0.f;
        float pua = 0.f, pub = 0.f, puc = 0.f, pud = 0.f;
#pragma unroll
        for (int j = 0; j < 16; ++j) {
            const float4 a  = q4[j];
            const float4 b  = u4[j];
            const float4 jv = *(const float4*)&jr[4 * j];
            pqa = fmaf(jv.x, a.x, pqa); pqb = fmaf(jv.y, a.y, pqb);
            pqc = fmaf(jv.z, a.z, pqc); pqd = fmaf(jv.w, a.w, pqd);
            pua = fmaf(jv.x, b.x, pua); pub = fmaf(jv.y, b.y, pub);
            puc = fmaf(jv.z, b.z, puc); pud = fmaf(jv.w, b.w, pud);
        }
        float pq = (pqa + pqb) + (pqc + pqd);
        float pu = (pua + pub) + (puc + pud);

        // ---- B: write partials ----
        part[w][lane] = make_float2(pq, pu);

        // ---- F: stage (s+2) data (regs loaded 1 iteration ago) ----
        if (roleA) sbuf[pw][0][sidx] = gstage;
        else       sbuf[pw][1][sidx] = gstage;

        // ---- C: issue global loads: q/u for s+3, v for s+3, scalars s+1 ----
        const int t3 = (s + 3 < SEQ) ? s + 3 : SEQ - 1;
        const int t1 = (s + 1 < SEQ) ? s + 1 : SEQ - 1;
        gstage = roleA ? q[(size_t)t3 * D + sidx] : U[(size_t)t3 * D + sidx];
        const float vnew = v[(size_t)t3 * D + r];
        const float  sln = sl_arr[t1], kqn = kqq_arr[t1], vvn = vv_arr[t1];
        const double invn = invl_arr[t1];

        __syncthreads();  // B1

        // ---- E: combine partner wave (same rows, other cols) + reduce ----
        {
            float2 o = part[w ^ 1][lane];
            pq += o.x;
            pu += o.y;
        }
        float x0, x1 = 0.f;
        if (g == 0) {
            x0 = vcur * pq;          // -> v^T J q
            x1 = pq * pq;            // -> |J q|^2
#pragma unroll
            for (int off = 1; off < 64; off <<= 1) {
                x0 += __shfl_xor(x0, off);
                x1 += __shfl_xor(x1, off);
            }
        } else {
            x0 = vcur * pu;          // -> v^T J u  (A_Jl)
#pragma unroll
            for (int off = 1; off < 64; off <<= 1) x0 += __shfl_xor(x0, off);
        }
        if (lane == 0) { wred[w][0] = x0; wred[w][1] = x1; }

        __syncthreads();  // B2

        // ---- H: k row load (latency hidden by fp64 chain) ----
        float4 kk[16];
        const float4* k4 = (const float4*)(k + (size_t)s * D + c0);
#pragma unroll
        for (int j = 0; j < 16; ++j) kk[j] = k4[j];

        const double Jqv = (double)wred[0][0] + (double)wred[2][0];
        const double Jq2 = (double)wred[0][1] + (double)wred[2][1];
        const double AJl = (double)wred[1][0] + (double)wred[3][0];

        // ---- redundant fp64 decision chain (identical on all threads) ----
        trSvv += (double)vvc;
        SJ    += Jqv;
        AJJ   += Jq2;
        const double s_l  = (double)slc;
        const double A_ll = (double)vvc * (double)kqc;
        const bool first = (s == 0);
        const double AJJ_s  = (first || AJJ == 0.0)  ? 1.0 : AJJ;   // > 0 always
        const double A_ll_s = (first || A_ll == 0.0) ? 1.0 : A_ll;
        const double denom   = AJJ * A_ll - AJl * AJl;
        const double denom_s = (first || denom == 0.0) ? 1.0 : denom;
        const double rden = 1.0 / denom_s;
        const double wf = (A_ll * SJ - AJl * s_l) * rden;
        const double wi = (AJJ * s_l - AJl * SJ) * rden;
        double wf_c, wi_c;
        if (wi <= 0.0)      { wf_c = SJ / AJJ_s;  wi_c = 0.0; }
        else if (wf <= 0.0) { wf_c = 0.0;         wi_c = s_l / A_ll_s; }
        else                { wf_c = wf;          wi_c = wi; }
        const bool do_update = (s_l * AJJ_s - AJl * SJ) > 0.0;  // margin * AJJ_s

        int mode;
        if (first) {
            mode = 2;
            SJ  = s_l;    // tr(vk^T Sqv') = k^T Sqv' v
            AJJ = A_ll;   // (v.v)(k^T Sqq' k)
        } else if (do_update) {
            mode = 1;
            const double nSJ = wf_c * SJ + wi_c * s_l;
            AJJ = wf_c * wf_c * AJJ + 2.0 * wf_c * wi_c * AJl + wi_c * wi_c * A_ll;
            SJ = nSJ;
        } else {
            mode = 0;
        }

        if (tid == 0) {
            out[s] = (float)((0.5 * trSvv - SJ + 0.5 * AJJ) * invc);
            out[SEQ + s] = (mode != 0) ? 1.f : 0.f;
        }

        // ---- I: J update (wave-uniform branch; no LDS touched here) ----
        if (mode == 2) {
#pragma unroll
            for (int j = 0; j < 16; ++j) {
                jr[4 * j + 0] = vcur * kk[j].x;
                jr[4 * j + 1] = vcur * kk[j].y;
                jr[4 * j + 2] = vcur * kk[j].z;
                jr[4 * j + 3] = vcur * kk[j].w;
            }
        } else if (mode == 1) {
            const float wff = (float)wf_c;
            const float wvr = (float)wi_c * vcur;
#pragma unroll
            for (int j = 0; j < 16; ++j) {
                jr[4 * j + 0] = fmaf(jr[4 * j + 0], wff, wvr * kk[j].x);
                jr[4 * j + 1] = fmaf(jr[4 * j + 1], wff, wvr * kk[j].y);
                jr[4 * j + 2] = fmaf(jr[4 * j + 2], wff, wvr * kk[j].z);
                jr[4 * j + 3] = fmaf(jr[4 * j + 3], wff, wvr * kk[j].w);
            }
        }

        // ---- shifts ----
        vcur = v1; v1 = v2; v2 = vnew;
        slc = sln; kqc = kqn; vvc = vvn; invc = invn;
    }

    // final J (row-major [d_v][d_k])
#pragma unroll
    for (int j = 0; j < 64; ++j) out[2 * SEQ + (size_t)r * D + c0 + j] = jr[j];
}

extern "C" void kernel_launch(void* const* d_in, const int* in_sizes, int n_in,
                              void* d_out, int out_size, void* d_ws, size_t ws_size,
                              hipStream_t stream) {
    (void)in_sizes; (void)n_in; (void)out_size; (void)ws_size;
    const float* q = (const float*)d_in[0];
    const float* k = (const float*)d_in[1];
    const float* v = (const float*)d_in[2];
    float* out = (float*)d_out;

    float* U    = (float*)d_ws;             // SEQ*D floats (1 MB)
    float* sl   = U + (size_t)SEQ * D;      // SEQ
    float* kqq  = sl + SEQ;                 // SEQ
    float* vv   = kqq + SEQ;                // SEQ
    double* invl = (double*)(vv + SEQ);     // SEQ doubles (8B-aligned)

    precompute_kernel<<<SEQ, 256, 0, stream>>>(q, k, v, U, sl, kqq, vv, invl);
    scan_kernel<<<1, 256, 0, stream>>>(q, k, v, U, sl, kqq, vv, invl, out);
}